// Round 5
// baseline (1932.636 us; speedup 1.0000x reference)
//
#include <hip/hip_runtime.h>
#include <hip/hip_bf16.h>

typedef __attribute__((ext_vector_type(8))) short   short8;
typedef __attribute__((ext_vector_type(8))) __bf16  bf16x8;
typedef __attribute__((ext_vector_type(4))) float   floatx4;

#define ALPHA_ 0.1f

__device__ inline bf16x8 cvt8(const float* p) {
    short8 r;
#pragma unroll
    for (int i = 0; i < 8; i++)
        r[i] = __builtin_bit_cast(short, __float2bfloat16(p[i]));
    return __builtin_bit_cast(bf16x8, r);
}

// ---------------- CSR build ----------------

__global__ void count_kernel(const int* __restrict__ col, int* __restrict__ icnt, int E) {
    int e = blockIdx.x * 256 + threadIdx.x;
    if (e < E) atomicAdd(&icnt[col[e]], 1);
}

__global__ void dinv_cursor_kernel(const int* __restrict__ icnt, float* __restrict__ dinv,
                                   int* __restrict__ cursor, int N) {
    int i = blockIdx.x * 256 + threadIdx.x;
    if (i < N) { dinv[i] = rsqrtf((float)(icnt[i] + 1)); cursor[i] = 0; }
}

__global__ __launch_bounds__(1024) void scan_kernel(const int* __restrict__ icnt,
                                                    int* __restrict__ offs, int N) {
    __shared__ int part[1024];
    int t = threadIdx.x;
    int CH = (N + 1023) >> 10;
    int base = t * CH;
    int s = 0;
    for (int i = 0; i < CH; i++) { int idx = base + i; if (idx < N) s += icnt[idx]; }
    part[t] = s;
    __syncthreads();
    for (int o = 1; o < 1024; o <<= 1) {
        int u = (t >= o) ? part[t - o] : 0;
        __syncthreads();
        part[t] += u;
        __syncthreads();
    }
    int off = part[t] - s;  // exclusive prefix
    for (int i = 0; i < CH; i++) {
        int idx = base + i;
        if (idx < N) { offs[idx] = off; off += icnt[idx]; }
    }
    if (t == 1023) offs[N] = part[1023];
}

__global__ void scatter_kernel(const int* __restrict__ row, const int* __restrict__ col,
                               const int* __restrict__ offs, int* __restrict__ cursor,
                               int* __restrict__ csr, int E) {
    int e = blockIdx.x * 256 + threadIdx.x;
    if (e < E) {
        int c = col[e];
        int p = offs[c] + atomicAdd(&cursor[c], 1);
        csr[p] = row[e];
    }
}

// ---------------- weight transpose f32 -> bf16 ----------------

__global__ void transpose_cvt_kernel(const float* __restrict__ src,
                                     __hip_bfloat16* __restrict__ dst, int K, int N) {
    int t = blockIdx.x * 256 + threadIdx.x;
    if (t < K * N) { int k = t / N, n = t % N; dst[n * K + k] = __float2bfloat16(src[t]); }
}

// ---------------- fused MLP: h = relu(x@W1+b1)@W2+b2 (bf16 MFMA, f32 x in) ----
// One block = 128 rows, 4 waves x 32 rows. Phase A: full 128x256 intermediate
// in registers (2x16 tiles/wave); 64-col strips round-trip LDS (D-layout ->
// A-operand layout) feeding phase B (2x4 tiles -> 128x64 h, stored bf16).

__global__ __launch_bounds__(256) void mlp_kernel(
    const float* __restrict__ x, const __hip_bfloat16* __restrict__ W1T,
    const float* __restrict__ b1, const __hip_bfloat16* __restrict__ W2T,
    const float* __restrict__ b2, __hip_bfloat16* __restrict__ h, int M)
{
    __shared__ __align__(16) __hip_bfloat16 Ts[128 * 72];  // 64-col strip, pad 64->72
    const int t = threadIdx.x;
    const int lane = t & 63, wave = t >> 6;
    const int lm = lane & 15, quad = lane >> 4;
    const int block_m = blockIdx.x * 128;
    const short* w1s = (const short*)W1T;
    const short* w2s = (const short*)W2T;

    floatx4 accA[2][16];
#pragma unroll
    for (int i = 0; i < 2; i++)
#pragma unroll
        for (int j = 0; j < 16; j++) accA[i][j] = (floatx4){0.f, 0.f, 0.f, 0.f};

    float zero8[8] = {0.f, 0.f, 0.f, 0.f, 0.f, 0.f, 0.f, 0.f};
    for (int k0 = 0; k0 < 512; k0 += 32) {
        bf16x8 af[2];
#pragma unroll
        for (int mt = 0; mt < 2; mt++) {
            int rowg = block_m + wave * 32 + mt * 16 + lm;
            const float* px = (rowg < M) ? &x[(size_t)rowg * 512 + k0 + quad * 8] : zero8;
            af[mt] = cvt8(px);
        }
#pragma unroll
        for (int nt = 0; nt < 16; nt++) {
            bf16x8 bfr = __builtin_bit_cast(bf16x8,
                *(const short8*)&w1s[(size_t)(nt * 16 + lm) * 512 + k0 + quad * 8]);
            accA[0][nt] = __builtin_amdgcn_mfma_f32_16x16x32_bf16(af[0], bfr, accA[0][nt], 0, 0, 0);
            accA[1][nt] = __builtin_amdgcn_mfma_f32_16x16x32_bf16(af[1], bfr, accA[1][nt], 0, 0, 0);
        }
    }

    floatx4 accB[2][4];
#pragma unroll
    for (int i = 0; i < 2; i++)
#pragma unroll
        for (int j = 0; j < 4; j++) accB[i][j] = (floatx4){0.f, 0.f, 0.f, 0.f};

#pragma unroll
    for (int s = 0; s < 4; s++) {
        __syncthreads();  // Ts reuse protection
        // write strip s (cols s*64..s*64+64) with bias+relu; D-layout source
#pragma unroll
        for (int mt = 0; mt < 2; mt++) {
#pragma unroll
            for (int ntl = 0; ntl < 4; ntl++) {
                int nt = s * 4 + ntl;
                float bv = b1[nt * 16 + lm];
#pragma unroll
                for (int r = 0; r < 4; r++) {
                    int rowl = wave * 32 + mt * 16 + quad * 4 + r;
                    float v = accA[mt][nt][r] + bv;
                    Ts[rowl * 72 + ntl * 16 + lm] = __float2bfloat16(fmaxf(v, 0.f));
                }
            }
        }
        __syncthreads();
        // phase B partial over K-chunk [s*64, s*64+64)
#pragma unroll
        for (int kk = 0; kk < 2; kk++) {
            bf16x8 af2[2];
#pragma unroll
            for (int mt = 0; mt < 2; mt++)
                af2[mt] = __builtin_bit_cast(bf16x8,
                    *(const short8*)&Ts[(wave * 32 + mt * 16 + lm) * 72 + kk * 32 + quad * 8]);
#pragma unroll
            for (int nt = 0; nt < 4; nt++) {
                bf16x8 bfr = __builtin_bit_cast(bf16x8,
                    *(const short8*)&w2s[(size_t)(nt * 16 + lm) * 256 + s * 64 + kk * 32 + quad * 8]);
                accB[0][nt] = __builtin_amdgcn_mfma_f32_16x16x32_bf16(af2[0], bfr, accB[0][nt], 0, 0, 0);
                accB[1][nt] = __builtin_amdgcn_mfma_f32_16x16x32_bf16(af2[1], bfr, accB[1][nt], 0, 0, 0);
            }
        }
    }

    // epilogue: D layout col=lane&15, row=quad*4+reg
#pragma unroll
    for (int mt = 0; mt < 2; mt++) {
#pragma unroll
        for (int nt = 0; nt < 4; nt++) {
            int colg = nt * 16 + lm;
            float bv = b2[colg];
#pragma unroll
            for (int r = 0; r < 4; r++) {
                int rowg = block_m + wave * 32 + mt * 16 + quad * 4 + r;
                if (rowg < M)
                    h[(size_t)rowg * 64 + colg] = __float2bfloat16(accB[mt][nt][r] + bv);
            }
        }
    }
}

// ---------------- propagation: one wave per node, lane = feature ----------------

__global__ __launch_bounds__(256) void prop_kernel(
    const __hip_bfloat16* __restrict__ z_in, const __hip_bfloat16* __restrict__ h,
    const float* __restrict__ dinv, const int* __restrict__ offs,
    const int* __restrict__ csr, __hip_bfloat16* __restrict__ z_out,
    float* __restrict__ out, int N, int last)
{
    int node = blockIdx.x * 4 + (threadIdx.x >> 6);
    if (node >= N) return;  // wave-uniform
    int lane = threadIdx.x & 63;
    float di = dinv[node];
    int s = offs[node], e = offs[node + 1];
    float acc = 0.f;
    for (int j0 = s; j0 < e; j0 += 64) {
        int jj = j0 + lane;
        int nbr = 0; float dn = 0.f;
        if (jj < e) { nbr = csr[jj]; dn = dinv[nbr]; }
        int cnt = min(64, e - j0);
        int tt = 0;
        for (; tt + 4 <= cnt; tt += 4) {
            int   nb0 = __shfl(nbr, tt + 0); float w0 = __shfl(dn, tt + 0);
            int   nb1 = __shfl(nbr, tt + 1); float w1 = __shfl(dn, tt + 1);
            int   nb2 = __shfl(nbr, tt + 2); float w2 = __shfl(dn, tt + 2);
            int   nb3 = __shfl(nbr, tt + 3); float w3 = __shfl(dn, tt + 3);
            float z0 = __bfloat162float(z_in[(size_t)nb0 * 64 + lane]);
            float z1 = __bfloat162float(z_in[(size_t)nb1 * 64 + lane]);
            float z2 = __bfloat162float(z_in[(size_t)nb2 * 64 + lane]);
            float z3 = __bfloat162float(z_in[(size_t)nb3 * 64 + lane]);
            acc += w0 * z0; acc += w1 * z1; acc += w2 * z2; acc += w3 * z3;
        }
        for (; tt < cnt; tt++) {
            int nb = __shfl(nbr, tt); float wv = __shfl(dn, tt);
            acc += wv * __bfloat162float(z_in[(size_t)nb * 64 + lane]);
        }
    }
    float zi = __bfloat162float(z_in[(size_t)node * 64 + lane]);
    float hv = __bfloat162float(h[(size_t)node * 64 + lane]);
    float v = (1.f - ALPHA_) * (di * acc + di * di * zi) + ALPHA_ * hv;
    if (!last) {
        z_out[(size_t)node * 64 + lane] = __float2bfloat16(v);
    } else {
        float m = v;
#pragma unroll
        for (int o = 32; o > 0; o >>= 1) m = fmaxf(m, __shfl_xor(m, o));
        float ex = expf(v - m);
        float ssum = ex;
#pragma unroll
        for (int o = 32; o > 0; o >>= 1) ssum += __shfl_xor(ssum, o);
        out[(size_t)node * 64 + lane] = v - m - logf(ssum);
    }
}

// ---------------- launch ----------------

extern "C" void kernel_launch(void* const* d_in, const int* in_sizes, int n_in,
                              void* d_out, int out_size, void* d_ws, size_t ws_size,
                              hipStream_t stream) {
    // Reference dtypes: all float32 except edge_index (int32). Output float32.
    const float* x  = (const float*)d_in[0];
    const int*   ei = (const int*)d_in[1];
    const float* W1 = (const float*)d_in[2];
    const float* b1 = (const float*)d_in[3];
    const float* W2 = (const float*)d_in[4];
    const float* b2 = (const float*)d_in[5];
    float* out = (float*)d_out;

    const int FIN = 512, FH = 256, FO = 64;
    const int N = in_sizes[0] / FIN;
    const int E = in_sizes[1] / 2;
    const int* erow = ei;
    const int* ecol = ei + E;

    char* w = (char*)d_ws;
    size_t o = 0;
    auto take = [&](size_t bytes) -> void* {
        void* p = w + o;
        o += (bytes + 511) & ~(size_t)511;
        return p;
    };
    // total ~40.3 MB (zB lives in d_out's first half; dead by the final write)
    int*   icnt   = (int*)  take((size_t)N * 4);
    float* dinv   = (float*)take((size_t)N * 4);
    int*   offs   = (int*)  take((size_t)(N + 1) * 4);
    int*   cursor = (int*)  take((size_t)N * 4);
    int*   csr    = (int*)  take((size_t)E * 4);
    __hip_bfloat16* W1T  = (__hip_bfloat16*)take((size_t)FIN * FH * 2);
    __hip_bfloat16* W2T  = (__hip_bfloat16*)take((size_t)FH * FO * 2);
    __hip_bfloat16* hbuf = (__hip_bfloat16*)take((size_t)N * FO * 2);
    __hip_bfloat16* zA   = (__hip_bfloat16*)take((size_t)N * FO * 2);
    __hip_bfloat16* zB   = (__hip_bfloat16*)out;  // alias: bf16 z (12.8 MB) fits in
                                                  // f32 out (25.6 MB); k=9 reads zA
                                                  // and fully overwrites out.

    hipMemsetAsync(icnt, 0, (size_t)N * 4, stream);
    count_kernel<<<(E + 255) / 256, 256, 0, stream>>>(ecol, icnt, E);
    dinv_cursor_kernel<<<(N + 255) / 256, 256, 0, stream>>>(icnt, dinv, cursor, N);
    scan_kernel<<<1, 1024, 0, stream>>>(icnt, offs, N);
    scatter_kernel<<<(E + 255) / 256, 256, 0, stream>>>(erow, ecol, offs, cursor, csr, E);
    transpose_cvt_kernel<<<(FIN * FH + 255) / 256, 256, 0, stream>>>(W1, W1T, FIN, FH);
    transpose_cvt_kernel<<<(FH * FO + 255) / 256, 256, 0, stream>>>(W2, W2T, FH, FO);

    mlp_kernel<<<(N + 127) / 128, 256, 0, stream>>>(x, W1T, b1, W2T, b2, hbuf, N);

    const __hip_bfloat16* zin = hbuf;
    for (int k = 0; k < 10; k++) {
        int last = (k == 9);
        __hip_bfloat16* zout = (k & 1) ? zB : zA;
        prop_kernel<<<(N + 3) / 4, 256, 0, stream>>>(zin, hbuf, dinv, offs, csr,
                                                     zout, out, N, last);
        zin = zout;
    }
}

// Round 7
// 1602.429 us; speedup vs baseline: 1.2061x; 1.2061x over previous
//
#include <hip/hip_runtime.h>
#include <hip/hip_bf16.h>

typedef __attribute__((ext_vector_type(8))) short   short8;
typedef __attribute__((ext_vector_type(4))) short   shortx4;
typedef __attribute__((ext_vector_type(8))) __bf16  bf16x8;
typedef __attribute__((ext_vector_type(4))) float   floatx4;

__device__ inline float bf2f(short u) {
    return __builtin_bit_cast(float, (unsigned)((unsigned short)u) << 16);
}
__device__ inline short f2bf(float f) {
    return __builtin_bit_cast(short, __float2bfloat16(f));
}

// ---------------- CSR build ----------------

__global__ void count_kernel(const int* __restrict__ col, int* __restrict__ icnt, int E) {
    int e = blockIdx.x * 256 + threadIdx.x;
    if (e < E) atomicAdd(&icnt[col[e]], 1);
}

__global__ void dinv_cursor_kernel(const int* __restrict__ icnt, float* __restrict__ dinv,
                                   int* __restrict__ cursor, int N) {
    int i = blockIdx.x * 256 + threadIdx.x;
    if (i < N) { dinv[i] = rsqrtf((float)(icnt[i] + 1)); cursor[i] = 0; }
}

__global__ __launch_bounds__(1024) void scan_kernel(const int* __restrict__ icnt,
                                                    int* __restrict__ offs, int N) {
    __shared__ int part[1024];
    int t = threadIdx.x;
    int CH = (N + 1023) >> 10;
    int base = t * CH;
    int s = 0;
    for (int i = 0; i < CH; i++) { int idx = base + i; if (idx < N) s += icnt[idx]; }
    part[t] = s;
    __syncthreads();
    for (int o = 1; o < 1024; o <<= 1) {
        int u = (t >= o) ? part[t - o] : 0;
        __syncthreads();
        part[t] += u;
        __syncthreads();
    }
    int off = part[t] - s;
    for (int i = 0; i < CH; i++) {
        int idx = base + i;
        if (idx < N) { offs[idx] = off; off += icnt[idx]; }
    }
    if (t == 1023) offs[N] = part[1023];
}

__global__ void scatter_kernel(const int* __restrict__ row, const int* __restrict__ col,
                               const int* __restrict__ offs, int* __restrict__ cursor,
                               int* __restrict__ csr, int E) {
    int e = blockIdx.x * 256 + threadIdx.x;
    if (e < E) {
        int c = col[e];
        int p = offs[c] + atomicAdd(&cursor[c], 1);
        csr[p] = row[e];
    }
}

// ---------------- weight prep ----------------

// W1 [512][256] f32 -> tiled bf16 [16][256][32]: k-chunk kc holds a contiguous
// 16 KB tile (n-major, 32 k's), so mlp staging reads are fully coalesced.
__global__ void w1_tile_kernel(const float* __restrict__ src,
                               __hip_bfloat16* __restrict__ dst) {
    int t = blockIdx.x * 256 + threadIdx.x;
    if (t < 512 * 256) {
        int k = t >> 8, n = t & 255;
        dst[(k >> 5) * 8192 + n * 32 + (k & 31)] = __float2bfloat16(src[t]);
    }
}

// W2 [256][64] f32 -> W2T [64][256] bf16
__global__ void transpose_cvt_kernel(const float* __restrict__ src,
                                     __hip_bfloat16* __restrict__ dst, int K, int N) {
    int t = blockIdx.x * 256 + threadIdx.x;
    if (t < K * N) { int k = t / N, n = t % N; dst[n * K + k] = __float2bfloat16(src[t]); }
}

// ---------------- fused MLP: h = relu(x@W1+b1)@W2+b2 ----------------
// LDS-staged phase A (x f32->bf16 conversion during staging; W1 from tiled
// layout), full 128x256 intermediate in registers, strip round-trip via LDS
// into phase B. h stored bf16 [N][64].

__global__ __launch_bounds__(256) void mlp_kernel(
    const float* __restrict__ x, const __hip_bfloat16* __restrict__ W1Tt,
    const float* __restrict__ b1, const __hip_bfloat16* __restrict__ W2T,
    const float* __restrict__ b2, __hip_bfloat16* __restrict__ h, int M)
{
    __shared__ __align__(16) short lds[5120 + 10240];  // a:128x40 | b:256x40
    short* lds_a = lds;
    short* lds_b = lds + 5120;
    short* Ts    = lds;  // 128x72 strip buffer for phase B (aliases; 9216 shorts)

    const int t = threadIdx.x;
    const int lane = t & 63, wave = t >> 6;
    const int lm = lane & 15, quad = lane >> 4;
    const int block_m = blockIdx.x * 128;
    const short* w1s = (const short*)W1Tt;
    const short* w2s = (const short*)W2T;

    floatx4 accA[2][16];
#pragma unroll
    for (int i = 0; i < 2; i++)
#pragma unroll
        for (int j = 0; j < 16; j++) accA[i][j] = (floatx4){0.f, 0.f, 0.f, 0.f};

    for (int kc = 0; kc < 16; kc++) {
        // stage A: 128x32 f32 -> bf16 LDS (1024 float4 slots, 4/thread)
#pragma unroll
        for (int r = 0; r < 4; r++) {
            int slot = t + 256 * r;
            int row = slot >> 3, c4 = slot & 7;
            int grow = block_m + row;
            floatx4 v = (floatx4){0.f, 0.f, 0.f, 0.f};
            if (grow < M) v = *(const floatx4*)&x[(size_t)grow * 512 + kc * 32 + c4 * 4];
            shortx4 bb;
#pragma unroll
            for (int j = 0; j < 4; j++) bb[j] = f2bf(v[j]);
            *(shortx4*)&lds_a[row * 40 + c4 * 4] = bb;
        }
        // stage B: contiguous 16 KB tile (1024 short8 chunks, 4/thread, coalesced)
#pragma unroll
        for (int r = 0; r < 4; r++) {
            int c = t + 256 * r;
            short8 v = *(const short8*)&w1s[(size_t)kc * 8192 + c * 8];
            *(short8*)&lds_b[(c >> 2) * 40 + (c & 3) * 8] = v;
        }
        __syncthreads();

        bf16x8 af[2];
#pragma unroll
        for (int mt = 0; mt < 2; mt++)
            af[mt] = __builtin_bit_cast(bf16x8,
                *(const short8*)&lds_a[(wave * 32 + mt * 16 + lm) * 40 + quad * 8]);
#pragma unroll
        for (int nt = 0; nt < 16; nt++) {
            bf16x8 bfr = __builtin_bit_cast(bf16x8,
                *(const short8*)&lds_b[(nt * 16 + lm) * 40 + quad * 8]);
            accA[0][nt] = __builtin_amdgcn_mfma_f32_16x16x32_bf16(af[0], bfr, accA[0][nt], 0, 0, 0);
            accA[1][nt] = __builtin_amdgcn_mfma_f32_16x16x32_bf16(af[1], bfr, accA[1][nt], 0, 0, 0);
        }
        __syncthreads();
    }

    floatx4 accB[2][4];
#pragma unroll
    for (int i = 0; i < 2; i++)
#pragma unroll
        for (int j = 0; j < 4; j++) accB[i][j] = (floatx4){0.f, 0.f, 0.f, 0.f};

#pragma unroll
    for (int s = 0; s < 4; s++) {
        __syncthreads();
        // strip s (cols s*64..s*64+64), bias+relu, D-layout -> LDS
#pragma unroll
        for (int mt = 0; mt < 2; mt++) {
#pragma unroll
            for (int ntl = 0; ntl < 4; ntl++) {
                int nt = s * 4 + ntl;
                float bv = b1[nt * 16 + lm];
#pragma unroll
                for (int r = 0; r < 4; r++) {
                    int rowl = wave * 32 + mt * 16 + quad * 4 + r;
                    Ts[rowl * 72 + ntl * 16 + lm] = f2bf(fmaxf(accA[mt][nt][r] + bv, 0.f));
                }
            }
        }
        __syncthreads();
#pragma unroll
        for (int kk = 0; kk < 2; kk++) {
            bf16x8 af2[2];
#pragma unroll
            for (int mt = 0; mt < 2; mt++)
                af2[mt] = __builtin_bit_cast(bf16x8,
                    *(const short8*)&Ts[(wave * 32 + mt * 16 + lm) * 72 + kk * 32 + quad * 8]);
#pragma unroll
            for (int nt = 0; nt < 4; nt++) {
                bf16x8 bfr = __builtin_bit_cast(bf16x8,
                    *(const short8*)&w2s[(size_t)(nt * 16 + lm) * 256 + s * 64 + kk * 32 + quad * 8]);
                accB[0][nt] = __builtin_amdgcn_mfma_f32_16x16x32_bf16(af2[0], bfr, accB[0][nt], 0, 0, 0);
                accB[1][nt] = __builtin_amdgcn_mfma_f32_16x16x32_bf16(af2[1], bfr, accB[1][nt], 0, 0, 0);
            }
        }
    }

    // epilogue: D layout col=lane&15, row=quad*4+reg
#pragma unroll
    for (int mt = 0; mt < 2; mt++) {
#pragma unroll
        for (int nt = 0; nt < 4; nt++) {
            int colg = nt * 16 + lm;
            float bv = b2[colg];
#pragma unroll
            for (int r = 0; r < 4; r++) {
                int rowg = block_m + wave * 32 + mt * 16 + quad * 4 + r;
                if (rowg < M)
                    h[(size_t)rowg * 64 + colg] = __float2bfloat16(accB[mt][nt][r] + bv);
            }
        }
    }
}

// ---------------- propagation: wave/node; 8 groups x 8-feature chunks ----------
// One wave = 8 neighbor groups (g) x 8 feature chunks (i). Each gather instr
// moves 8 full z rows (1 KB/wave) instead of 1 (128 B). Group partials are
// combined with 3 shfl_xor rounds at the end.

__global__ __launch_bounds__(256) void prop_kernel(
    const __hip_bfloat16* __restrict__ z_in, const __hip_bfloat16* __restrict__ h,
    const float* __restrict__ dinv, const int* __restrict__ offs,
    const int* __restrict__ csr, __hip_bfloat16* __restrict__ z_out,
    float* __restrict__ out, int N, int last)
{
    int node = blockIdx.x * 4 + (threadIdx.x >> 6);
    if (node >= N) return;  // wave-uniform
    int lane = threadIdx.x & 63;
    int g = lane >> 3, i = lane & 7;
    const short* zs = (const short*)z_in;
    const short* hs = (const short*)h;
    float di = dinv[node];
    int s = offs[node], e = offs[node + 1];
    float acc[8] = {0.f, 0.f, 0.f, 0.f, 0.f, 0.f, 0.f, 0.f};

    for (int j0 = s; j0 < e; j0 += 64) {
        int jj = j0 + lane;
        int nbr = 0; float dn = 0.f;
        if (jj < e) { nbr = csr[jj]; dn = dinv[nbr]; }
        int cnt = min(64, e - j0);
        int tmax = (cnt + 7) >> 3;
        for (int tt = 0; tt < tmax; tt++) {
            int src = tt * 8 + g;           // interleaved positions: early exit works
            int nb = __shfl(nbr, src);
            float wv = __shfl(dn, src);     // 0 for padded slots
            short8 zv = *(const short8*)&zs[(size_t)nb * 64 + i * 8];
#pragma unroll
            for (int j = 0; j < 8; j++)
                acc[j] = fmaf(wv, bf2f(zv[j]), acc[j]);
        }
    }
    // combine the 8 neighbor groups
#pragma unroll
    for (int j = 0; j < 8; j++) {
        acc[j] += __shfl_xor(acc[j], 8);
        acc[j] += __shfl_xor(acc[j], 16);
        acc[j] += __shfl_xor(acc[j], 32);
    }

    short8 zv = *(const short8*)&zs[(size_t)node * 64 + i * 8];
    short8 hv = *(const short8*)&hs[(size_t)node * 64 + i * 8];
    float v[8];
#pragma unroll
    for (int j = 0; j < 8; j++)
        v[j] = 0.9f * (di * acc[j] + di * di * bf2f(zv[j])) + 0.1f * bf2f(hv[j]);

    if (!last) {
        if (g == 0) {
            short8 o8;
#pragma unroll
            for (int j = 0; j < 8; j++) o8[j] = f2bf(v[j]);
            *(short8*)&((short*)z_out)[(size_t)node * 64 + i * 8] = o8;
        }
    } else {
        float m = v[0];
#pragma unroll
        for (int j = 1; j < 8; j++) m = fmaxf(m, v[j]);
        m = fmaxf(m, __shfl_xor(m, 1));
        m = fmaxf(m, __shfl_xor(m, 2));
        m = fmaxf(m, __shfl_xor(m, 4));
        float ss = 0.f;
#pragma unroll
        for (int j = 0; j < 8; j++) ss += expf(v[j] - m);
        ss += __shfl_xor(ss, 1);
        ss += __shfl_xor(ss, 2);
        ss += __shfl_xor(ss, 4);
        float ls = m + logf(ss);
        if (g == 0) {
            floatx4 o0, o1;
#pragma unroll
            for (int j = 0; j < 4; j++) { o0[j] = v[j] - ls; o1[j] = v[4 + j] - ls; }
            *(floatx4*)&out[(size_t)node * 64 + i * 8]     = o0;
            *(floatx4*)&out[(size_t)node * 64 + i * 8 + 4] = o1;
        }
    }
}

// ---------------- launch ----------------

extern "C" void kernel_launch(void* const* d_in, const int* in_sizes, int n_in,
                              void* d_out, int out_size, void* d_ws, size_t ws_size,
                              hipStream_t stream) {
    const float* x  = (const float*)d_in[0];
    const int*   ei = (const int*)d_in[1];
    const float* W1 = (const float*)d_in[2];
    const float* b1 = (const float*)d_in[3];
    const float* W2 = (const float*)d_in[4];
    const float* b2 = (const float*)d_in[5];
    float* out = (float*)d_out;

    const int FIN = 512, FH = 256, FO = 64;
    const int N = in_sizes[0] / FIN;
    const int E = in_sizes[1] / 2;
    const int* erow = ei;
    const int* ecol = ei + E;

    char* w = (char*)d_ws;
    size_t o = 0;
    auto take = [&](size_t bytes) -> void* {
        void* p = w + o;
        o += (bytes + 511) & ~(size_t)511;
        return p;
    };
    int*   icnt   = (int*)  take((size_t)N * 4);
    float* dinv   = (float*)take((size_t)N * 4);
    int*   offs   = (int*)  take((size_t)(N + 1) * 4);
    int*   cursor = (int*)  take((size_t)N * 4);
    int*   csr    = (int*)  take((size_t)E * 4);
    __hip_bfloat16* W1Tt = (__hip_bfloat16*)take((size_t)FIN * FH * 2);
    __hip_bfloat16* W2T  = (__hip_bfloat16*)take((size_t)FH * FO * 2);
    __hip_bfloat16* hbuf = (__hip_bfloat16*)take((size_t)N * FO * 2);
    __hip_bfloat16* zA   = (__hip_bfloat16*)take((size_t)N * FO * 2);
    __hip_bfloat16* zB   = (__hip_bfloat16*)out;  // alias: bf16 z (12.8 MB) in f32 out
                                                  // (25.6 MB); k=9 reads zA, overwrites out

    (void)hipMemsetAsync(icnt, 0, (size_t)N * 4, stream);
    count_kernel<<<(E + 255) / 256, 256, 0, stream>>>(ecol, icnt, E);
    dinv_cursor_kernel<<<(N + 255) / 256, 256, 0, stream>>>(icnt, dinv, cursor, N);
    scan_kernel<<<1, 1024, 0, stream>>>(icnt, offs, N);
    scatter_kernel<<<(E + 255) / 256, 256, 0, stream>>>(erow, ecol, offs, cursor, csr, E);
    w1_tile_kernel<<<(FIN * FH + 255) / 256, 256, 0, stream>>>(W1, W1Tt);
    transpose_cvt_kernel<<<(FH * FO + 255) / 256, 256, 0, stream>>>(W2, W2T, FH, FO);

    mlp_kernel<<<(N + 127) / 128, 256, 0, stream>>>(x, W1Tt, b1, W2T, b2, hbuf, N);

    const __hip_bfloat16* zin = hbuf;
    for (int k = 0; k < 10; k++) {
        int last = (k == 9);
        __hip_bfloat16* zout = (k & 1) ? zB : zA;
        prop_kernel<<<(N + 3) / 4, 256, 0, stream>>>(zin, hbuf, dinv, offs, csr,
                                                     zout, out, N, last);
        zin = zout;
    }
}